// Round 1
// baseline (830.668 us; speedup 1.0000x reference)
//
#include <hip/hip_runtime.h>
#include <math.h>

// y solves y^3/3 + y = x  ⇔  y^3 + 3y = 3x (depressed cubic, p=3, q=3x).
// Closed form (Cardano / sinh identity):
//   y = u - 1/u,   u = cbrt(z + sqrt(z^2 + 1)),   z = 1.5*x
// y(x) is odd, so evaluate at |x| (then z >= 0, z + sqrt(z^2+1) >= 1: no
// cancellation in the cbrt argument) and restore the sign. cbrt via
// exp2(log2(a)/3) hardware trans ops (~1e-7 rel err), then ONE Newton
// polish step with live x — same structure as the reference's final step —
// which contracts method error to fp32 rounding. Replaces 7 serial Newton
// iterations (35 VALU + 7 trans per element) with ~13 VALU + 5 trans.

typedef float f32x4 __attribute__((ext_vector_type(4)));

__device__ __forceinline__ float exp2_fast(float x) {
#if __has_builtin(__builtin_amdgcn_exp2f)
    return __builtin_amdgcn_exp2f(x);
#else
    return exp2f(x);
#endif
}

__device__ __forceinline__ float log2_fast(float x) {
#if __has_builtin(__builtin_amdgcn_logf)
    return __builtin_amdgcn_logf(x);
#else
    return log2f(x);
#endif
}

__device__ __forceinline__ float sqrt_fast(float x) {
#if __has_builtin(__builtin_amdgcn_sqrtf)
    return __builtin_amdgcn_sqrtf(x);
#else
    return sqrtf(x);
#endif
}

__device__ __forceinline__ float nonsat_solve(float x) {
    float ax = fabsf(x);
    float z  = 1.5f * ax;
    float s  = sqrt_fast(__builtin_fmaf(z, z, 1.0f));   // sqrt(z^2 + 1)
    float a  = z + s;                                   // >= 1
    float u  = exp2_fast(0.33333333f * log2_fast(a));   // cbrt(a)
    float y  = u - __builtin_amdgcn_rcpf(u);            // u - 1/u  (>= 0)
    y = copysignf(y, x);
    // One Newton polish with live x: y' = (2/3 y^3 + x) / (y^2 + 1)
    float t   = y * y;
    float num = __builtin_fmaf(0.66666667f, t * y, x);
    float den = t + 1.0f;
    return num * __builtin_amdgcn_rcpf(den);
}

__global__ void __launch_bounds__(256)
nonsat_vec4_kernel(const f32x4* __restrict__ in, f32x4* __restrict__ out, int n4) {
    const int stride = (int)(gridDim.x * blockDim.x);
    for (int i = (int)(blockIdx.x * blockDim.x + threadIdx.x); i < n4; i += stride) {
        // Pure streaming, zero reuse: nontemporal to avoid L2/L3 pollution.
        f32x4 v = __builtin_nontemporal_load(&in[i]);
        f32x4 r;
        r.x = nonsat_solve(v.x);
        r.y = nonsat_solve(v.y);
        r.z = nonsat_solve(v.z);
        r.w = nonsat_solve(v.w);
        __builtin_nontemporal_store(r, &out[i]);
    }
}

__global__ void __launch_bounds__(256)
nonsat_tail_kernel(const float* __restrict__ in, float* __restrict__ out,
                   int start, int n) {
    int i = start + (int)(blockIdx.x * blockDim.x + threadIdx.x);
    if (i < n) out[i] = nonsat_solve(in[i]);
}

extern "C" void kernel_launch(void* const* d_in, const int* in_sizes, int n_in,
                              void* d_out, int out_size, void* d_ws, size_t ws_size,
                              hipStream_t stream) {
    const float* x = (const float*)d_in[0];
    float* out = (float*)d_out;
    int n = in_sizes[0];

    int n4 = n / 4;
    if (n4 > 0) {
        // Memory-bound: cap grid and grid-stride (guideline 11).
        // 4096 blocks x 256 thr = 1M threads, each looping ~32 float4s.
        int blocks = (n4 + 255) / 256;
        if (blocks > 4096) blocks = 4096;
        nonsat_vec4_kernel<<<blocks, 256, 0, stream>>>(
            (const f32x4*)x, (f32x4*)out, n4);
    }
    int rem_start = n4 * 4;
    if (rem_start < n) {
        int rem = n - rem_start;
        int blocks = (rem + 255) / 256;
        nonsat_tail_kernel<<<blocks, 256, 0, stream>>>(x, out, rem_start, n);
    }
}

// Round 2
// 803.084 us; speedup vs baseline: 1.0343x; 1.0343x over previous
//
#include <hip/hip_runtime.h>
#include <math.h>

// y solves y^3/3 + y = x  ⇔  y^3 + 3y = 3x (depressed cubic, p=3, q=3x).
// Closed form (Cardano / sinh identity):
//   y = u - 1/u,   u = cbrt(z + sqrt(z^2 + 1)),   z = 1.5*x
// y(x) is odd: evaluate at |x| (then a = z + sqrt(z^2+1) >= 1, no
// cancellation), restore sign, then ONE Newton polish with live x (same
// structure as the reference's final step) contracting method error to
// fp32 rounding. absmax vs reference is bit-identical to the 7-iteration
// Newton baseline (0.015625, dominated by the reference's early-stopped
// mean criterion, not our method error).
//
// Memory pattern: EXACTLY the measured-800us baseline config — one thread
// per float4, full one-shot grid, plain (cached) loads/stores. Round-1
// A/B showed nontemporal hints + 4096-block grid-stride cap cost +30us
// (+3.8%) on this pure-streaming kernel; reverted.

__device__ __forceinline__ float nonsat_solve(float x) {
    float ax = fabsf(x);
    float z  = 1.5f * ax;
    float s  = __builtin_amdgcn_sqrtf(__builtin_fmaf(z, z, 1.0f)); // sqrt(z^2+1)
    float a  = z + s;                                              // >= 1
    float u  = __builtin_amdgcn_exp2f(0.33333333f *
               __builtin_amdgcn_logf(a));                          // cbrt(a)
    float y  = u - __builtin_amdgcn_rcpf(u);                       // u - 1/u >= 0
    y = copysignf(y, x);
    // One Newton polish with live x: y' = (2/3 y^3 + x) / (y^2 + 1)
    float t   = y * y;
    float num = __builtin_fmaf(0.66666667f, t * y, x);
    float den = t + 1.0f;
    return num * __builtin_amdgcn_rcpf(den);
}

__global__ void __launch_bounds__(256)
nonsat_vec4_kernel(const float4* __restrict__ in, float4* __restrict__ out, int n4) {
    int i = blockIdx.x * blockDim.x + threadIdx.x;
    if (i < n4) {
        float4 v = in[i];
        v.x = nonsat_solve(v.x);
        v.y = nonsat_solve(v.y);
        v.z = nonsat_solve(v.z);
        v.w = nonsat_solve(v.w);
        out[i] = v;
    }
}

__global__ void __launch_bounds__(256)
nonsat_tail_kernel(const float* __restrict__ in, float* __restrict__ out,
                   int start, int n) {
    int i = start + blockIdx.x * blockDim.x + threadIdx.x;
    if (i < n) out[i] = nonsat_solve(in[i]);
}

extern "C" void kernel_launch(void* const* d_in, const int* in_sizes, int n_in,
                              void* d_out, int out_size, void* d_ws, size_t ws_size,
                              hipStream_t stream) {
    const float* x = (const float*)d_in[0];
    float* out = (float*)d_out;
    int n = in_sizes[0];

    int n4 = n / 4;
    if (n4 > 0) {
        int blocks = (n4 + 255) / 256;
        nonsat_vec4_kernel<<<blocks, 256, 0, stream>>>(
            (const float4*)x, (float4*)out, n4);
    }
    int rem_start = n4 * 4;
    if (rem_start < n) {
        int rem = n - rem_start;
        int blocks = (rem + 255) / 256;
        nonsat_tail_kernel<<<blocks, 256, 0, stream>>>(x, out, rem_start, n);
    }
}